// Round 5
// baseline (27395.148 us; speedup 1.0000x reference)
//
#include <hip/hip_runtime.h>
#include <math.h>

// Problem constants
#define BB 64      // batch
#define TT 512     // time steps
#define DD 256     // input dim
#define HH 512     // hidden dim
#define GG 2048    // 4*H
#define KX 768     // D+H concat K
#define K4 192     // KX/4 float4s per row
#define CTXF 49152 // context_state floats; traj_h starts after

// ---------------------------------------------------------------------------
// pack VU^T: vut[col][k] = k<D ? W[k][col] : U[k-D][col]
// ---------------------------------------------------------------------------
__global__ void pack_vut(const float* __restrict__ Wm, const float* __restrict__ Um,
                         float* __restrict__ vut) {
    __shared__ float tile[32][33];
    int k0 = blockIdx.x * 32;   // col block (2048)
    int j0 = blockIdx.y * 32;   // K block (768)
    int lx = threadIdx.x & 31;
    int ly = threadIdx.x >> 5;
    for (int r = ly; r < 32; r += 8) {
        int j = j0 + r, k = k0 + lx;
        tile[r][lx] = (j < DD) ? Wm[j * GG + k] : Um[(j - DD) * GG + k];
    }
    __syncthreads();
    for (int r = ly; r < 32; r += 8) {
        int k = k0 + r, j = j0 + lx;
        vut[(long)k * KX + j] = tile[lx][r];
    }
}

// zero h double-buffer + sync flags (ws is re-poisoned 0xAA before every launch)
__global__ void init_state(float* __restrict__ h, unsigned* __restrict__ flags) {
    int idx = blockIdx.x * 256 + threadIdx.x;
    if (idx < 2 * BB * HH) h[idx] = 0.f;
    if (idx < 256) flags[idx] = 0u;
}

// ---------------------------------------------------------------------------
// copy x into traj_h[:, :, 0:256] and context_state[:, 0:256]
// ---------------------------------------------------------------------------
__global__ void xcopy(const float* __restrict__ x, float* __restrict__ out) {
    const long n_traj = (long)BB * TT * (DD / 4);
    long idx = (long)blockIdx.x * 256 + threadIdx.x;
    const float4* x4 = (const float4*)x;
    float4* out4 = (float4*)out;
    if (idx < n_traj) {
        long bt = idx / (DD / 4);
        int d4 = (int)(idx % (DD / 4));
        out4[(CTXF / 4) + bt * (KX / 4) + d4] = x4[idx];
    } else if (idx < n_traj + BB * (DD / 4)) {
        long f = idx - n_traj;
        int b = (int)(f / (DD / 4)), d4 = (int)(f % (DD / 4));
        out4[(long)b * (KX / 4) + d4] = x4[((long)b * TT + (TT - 1)) * (DD / 4) + d4];
    }
}

// ---------------------------------------------------------------------------
// Persistent LSTM. 256 WGs x 512 threads, cooperative (co-residency only —
// NO grid.sync). WG(jb=wg&63, bg=wg>>6): j in [jb*8,+8) x batches [bg*16,+16).
// Cross-WG sync is per-batch-group (64 WGs) via release/acquire flags:
//   producer: h stores -> __syncthreads (vmcnt drain -> L2) -> tid0:
//             __threadfence (wbL2) + release-store flags[bg*64+jb]=t+1.
//   consumer: every thread acquire-polls flags[bg*64+(tid&63)] >= t (each
//             wave covers all 64 flags -> per-wave L1/L2 inv before h reads).
// Anti-overwrite: producer reaching step t+2's h-write passed the t+2 poll,
// which implies all group members finished t+1 and already read this buffer.
// ---------------------------------------------------------------------------
#define FMA4(A, Wv, Hv) \
    A.x += Wv.x * Hv.x; A.y += Wv.y * Hv.y; A.z += Wv.z * Hv.z; A.w += Wv.w * Hv.w;

__global__ __launch_bounds__(512) void lstm_persist(
    const float* __restrict__ vut, const float* __restrict__ bias,
    const float* __restrict__ x, float* __restrict__ h,
    unsigned* __restrict__ flags, float* __restrict__ out)
{
    __shared__ float4 w_lds[32 * K4];   // 98304 B, row r: [r*K4 + (k4 ^ (r&7))]
    __shared__ float4 xh[16 * K4];      // 49152 B, row b: [b*K4 + (k4 ^ (b&7))]
    __shared__ float  zsum[2][512];     //  4096 B, [parity][r*16 + b]

    const int wg = blockIdx.x;
    const int jb = wg & 63;
    const int bg = wg >> 6;
    const int b0 = bg * 16;
    const int j0 = jb * 8;
    const int tid = threadIdx.x;
    const int ks = tid >> 5;          // 0..15 K-slice
    const int ct = (tid >> 2) & 7;    // = jj
    const int bt = tid & 3;

    const float4* x4g = (const float4*)x;

    // ---- stage weights into LDS once (swizzled) ----
    for (int i = tid; i < 32 * K4; i += 512) {
        int r = i / K4;
        int k4 = i - r * K4;
        int col = (r >> 3) * HH + j0 + (r & 7);
        w_lds[r * K4 + (k4 ^ (r & 7))] =
            ((const float4*)(vut + (long)col * KX))[k4];
    }
    // ---- per-thread bias for zsum entry tid (r=tid>>4, b=tid&15) ----
    const int zr = tid >> 4;
    const float biasreg = bias[(zr >> 3) * HH + j0 + (zr & 7)];
    zsum[0][tid] = biasreg;

    float creg = 0.f;   // cell state for combiner threads (tid<128)

    // ---- x prefetch regs: items {tid, tid+512} of 1024 float4 ----
    const int xb1 = tid >> 6, xk1 = tid & 63;
    const int xb2 = 8 + xb1;
    float4 xp1 = x4g[((long)(b0 + xb1) * TT + 0) * 64 + xk1];
    float4 xp2 = x4g[((long)(b0 + xb2) * TT + 0) * 64 + xk1];

    // LDS base pointers for GEMM
    const float4* wl0 = &w_lds[(ct) * K4];
    const float4* wl1 = &w_lds[(8 + ct) * K4];
    const float4* wl2 = &w_lds[(16 + ct) * K4];
    const float4* wl3 = &w_lds[(24 + ct) * K4];
    const float4* xr0 = &xh[(bt) * K4];
    const float4* xr1 = &xh[(bt + 4) * K4];
    const float4* xr2 = &xh[(bt + 8) * K4];
    const float4* xr3 = &xh[(bt + 12) * K4];

    unsigned* const myflag   = &flags[bg * 64 + jb];
    unsigned* const pollflag = &flags[bg * 64 + (tid & 63)];

    for (int t = 0; t < TT; ++t) {
        const int p = t & 1;
        const float* hp = h + p * (BB * HH);
        float* hn = h + (1 - p) * (BB * HH);

        // ---- (a) stage x-part from prefetch regs; issue next-x loads ----
        xh[xb1 * K4 + (xk1 ^ (xb1 & 7))] = xp1;
        xh[xb2 * K4 + (xk1 ^ (xb2 & 7))] = xp2;
        if (t + 1 < TT) {
            xp1 = x4g[((long)(b0 + xb1) * TT + (t + 1)) * 64 + xk1];
            xp2 = x4g[((long)(b0 + xb2) * TT + (t + 1)) * 64 + xk1];
        }

        // ---- (b) wait until all 64 producers of this group finished t-1 ----
        if (t > 0) {
            const unsigned want = (unsigned)t;
            while (__hip_atomic_load(pollflag, __ATOMIC_ACQUIRE,
                                     __HIP_MEMORY_SCOPE_AGENT) < want) {
                __builtin_amdgcn_s_sleep(2);
            }
        }

        // ---- (c) stage h (fresh after acquire) ----
        #pragma unroll
        for (int s = 0; s < 4; ++s) {
            int i = tid + s * 512;          // 0..2047
            int b = i >> 7, k4h = i & 127;
            float4 v = ((const float4*)hp)[(b0 + b) * 128 + k4h];
            int k4 = 64 + k4h;
            xh[b * K4 + (k4 ^ (b & 7))] = v;
        }
        __syncthreads();

        // ---- (d) GEMM: 4 gate-cols x 4 batches per thread, K-slice of 48 ----
        float4 acc[4][4];
        #pragma unroll
        for (int g = 0; g < 4; ++g)
            #pragma unroll
            for (int s = 0; s < 4; ++s)
                acc[g][s] = make_float4(0.f, 0.f, 0.f, 0.f);

        #pragma unroll
        for (int it = 0; it < 12; ++it) {
            const int k4 = ks * 12 + it;
            const int kw  = k4 ^ ct;
            const int kh0 = k4 ^ bt;
            const int kh1 = k4 ^ (bt + 4);
            float4 w0v = wl0[kw], w1v = wl1[kw], w2v = wl2[kw], w3v = wl3[kw];
            float4 h0v = xr0[kh0], h1v = xr1[kh1], h2v = xr2[kh0], h3v = xr3[kh1];
            FMA4(acc[0][0], w0v, h0v); FMA4(acc[0][1], w0v, h1v);
            FMA4(acc[0][2], w0v, h2v); FMA4(acc[0][3], w0v, h3v);
            FMA4(acc[1][0], w1v, h0v); FMA4(acc[1][1], w1v, h1v);
            FMA4(acc[1][2], w1v, h2v); FMA4(acc[1][3], w1v, h3v);
            FMA4(acc[2][0], w2v, h0v); FMA4(acc[2][1], w2v, h1v);
            FMA4(acc[2][2], w2v, h2v); FMA4(acc[2][3], w2v, h3v);
            FMA4(acc[3][0], w3v, h0v); FMA4(acc[3][1], w3v, h1v);
            FMA4(acc[3][2], w3v, h2v); FMA4(acc[3][3], w3v, h3v);
        }
        #pragma unroll
        for (int g = 0; g < 4; ++g) {
            #pragma unroll
            for (int s = 0; s < 4; ++s) {
                float4 a = acc[g][s];
                float z = (a.x + a.y) + (a.z + a.w);
                atomicAdd(&zsum[p][(g * 8 + ct) * 16 + (bt + 4 * s)], z);
            }
        }
        __syncthreads();

        // ---- (e) re-init other parity buffer + gate combine + h publish ----
        zsum[1 - p][tid] = biasreg;
        if (tid < 128) {
            const int b = tid >> 3, jj = tid & 7;
            float zi = zsum[p][(jj) * 16 + b];
            float zf = zsum[p][(8 + jj) * 16 + b];
            float zg = zsum[p][(16 + jj) * 16 + b];
            float zo = zsum[p][(24 + jj) * 16 + b];
            float iv = tanhf(zi);
            float fv = tanhf(zf);
            float gv = tanhf(zg);
            float ov = tanhf(zo);
            float c2 = fv * creg + iv * gv;
            float h2 = ov * tanhf(c2);
            creg = c2;
            hn[(b0 + b) * HH + (j0 + jj)] = h2;
            out[CTXF + ((long)((b0 + b) * TT + t)) * KX + DD + (j0 + jj)] = h2;
            if (t == TT - 1) out[(long)(b0 + b) * KX + DD + (j0 + jj)] = h2;
        }
        __syncthreads();   // h stores drained (vmcnt) and WG-wide complete
        if (tid == 0) {
            __threadfence();   // wbL2: push this XCD's dirty lines to coherence point
            __hip_atomic_store(myflag, (unsigned)(t + 1),
                               __ATOMIC_RELEASE, __HIP_MEMORY_SCOPE_AGENT);
        }
    }
}

// ---------------------------------------------------------------------------
extern "C" void kernel_launch(void* const* d_in, const int* in_sizes, int n_in,
                              void* d_out, int out_size, void* d_ws, size_t ws_size,
                              hipStream_t stream) {
    (void)in_sizes; (void)n_in; (void)out_size; (void)ws_size;
    const float* x    = (const float*)d_in[0];
    const float* Wm   = (const float*)d_in[1];
    const float* Um   = (const float*)d_in[2];
    const float* bias = (const float*)d_in[3];
    float* out = (float*)d_out;
    float* ws  = (float*)d_ws;

    float* vut      = ws;                          // 2048*768 floats
    float* h        = ws + 1572864;                // 2 * 64*512 floats
    unsigned* flags = (unsigned*)(ws + 1572864 + 65536);  // 256 flags

    hipLaunchKernelGGL(pack_vut, dim3(64, 24), dim3(256), 0, stream, Wm, Um, vut);
    hipLaunchKernelGGL(init_state, dim3(256), dim3(256), 0, stream, h, flags);
    hipLaunchKernelGGL(xcopy, dim3(8209), dim3(256), 0, stream, x, out);

    void* args[] = {(void*)&vut, (void*)&bias, (void*)&x, (void*)&h,
                    (void*)&flags, (void*)&out};
    hipLaunchCooperativeKernel((const void*)lstm_persist, dim3(256), dim3(512),
                               args, 0, stream);
}

// Round 6
// 9085.041 us; speedup vs baseline: 3.0154x; 3.0154x over previous
//
#include <hip/hip_runtime.h>
#include <math.h>

// Problem constants
#define BB 64      // batch
#define TT 512     // time steps
#define DD 256     // input dim
#define HH 512     // hidden dim
#define GG 2048    // 4*H
#define KX 768     // D+H concat K
#define K4 192     // KX/4 float4s per row
#define CTXF 49152 // context_state floats; traj_h starts after

// ---------------------------------------------------------------------------
// pack VU^T: vut[col][k] = k<D ? W[k][col] : U[k-D][col]
// ---------------------------------------------------------------------------
__global__ void pack_vut(const float* __restrict__ Wm, const float* __restrict__ Um,
                         float* __restrict__ vut) {
    __shared__ float tile[32][33];
    int k0 = blockIdx.x * 32;   // col block (2048)
    int j0 = blockIdx.y * 32;   // K block (768)
    int lx = threadIdx.x & 31;
    int ly = threadIdx.x >> 5;
    for (int r = ly; r < 32; r += 8) {
        int j = j0 + r, k = k0 + lx;
        tile[r][lx] = (j < DD) ? Wm[j * GG + k] : Um[(j - DD) * GG + k];
    }
    __syncthreads();
    for (int r = ly; r < 32; r += 8) {
        int k = k0 + r, j = j0 + lx;
        vut[(long)k * KX + j] = tile[lx][r];
    }
}

// zero h double-buffer + sync flags (ws is re-poisoned 0xAA before every launch)
__global__ void init_state(float* __restrict__ h, unsigned* __restrict__ flags) {
    int idx = blockIdx.x * 256 + threadIdx.x;
    if (idx < 2 * BB * HH) h[idx] = 0.f;
    if (idx < 256) flags[idx] = 0u;
}

// ---------------------------------------------------------------------------
// copy x into traj_h[:, :, 0:256] and context_state[:, 0:256]
// ---------------------------------------------------------------------------
__global__ void xcopy(const float* __restrict__ x, float* __restrict__ out) {
    const long n_traj = (long)BB * TT * (DD / 4);
    long idx = (long)blockIdx.x * 256 + threadIdx.x;
    const float4* x4 = (const float4*)x;
    float4* out4 = (float4*)out;
    if (idx < n_traj) {
        long bt = idx / (DD / 4);
        int d4 = (int)(idx % (DD / 4));
        out4[(CTXF / 4) + bt * (KX / 4) + d4] = x4[idx];
    } else if (idx < n_traj + BB * (DD / 4)) {
        long f = idx - n_traj;
        int b = (int)(f / (DD / 4)), d4 = (int)(f % (DD / 4));
        out4[(long)b * (KX / 4) + d4] = x4[((long)b * TT + (TT - 1)) * (DD / 4) + d4];
    }
}

// ---------------------------------------------------------------------------
// Persistent LSTM. 256 WGs x 512 threads, cooperative (co-residency only).
// WG(jb=wg&63, bg=wg>>6): j in [jb*8,+8) x batches [bg*16,+16).
//
// FENCE-FREE cross-WG sync (R6 experiment): all h-state and flag traffic uses
// agent-scope RELAXED atomics (cache-bypassing, executed at the coherence
// point). NO threadfence / release / acquire => NO buffer_wbl2 / buffer_inv.
// Ordering: producer's __syncthreads() drains vmcnt(0), i.e. its h stores are
// ACKED at the coherence point before tid0 issues the flag store. Consumers
// poll flags (relaxed agent loads), then load h (relaxed agent loads) which
// fetch from the coherence point by construction — no stale-cache hazard.
// Anti-overwrite: a producer reaching step t+1's h-write passed the t+1 poll,
// which implies every group member finished step t and already read the
// buffer being overwritten (reads of h[1-p] at step t precede flag=t+1).
// ---------------------------------------------------------------------------
#define FMA4(A, Wv, Hv) \
    A.x += Wv.x * Hv.x; A.y += Wv.y * Hv.y; A.z += Wv.z * Hv.z; A.w += Wv.w * Hv.w;

__global__ __launch_bounds__(512) void lstm_persist(
    const float* __restrict__ vut, const float* __restrict__ bias,
    const float* __restrict__ x, float* __restrict__ h,
    unsigned* __restrict__ flags, float* __restrict__ out)
{
    __shared__ float4 w_lds[32 * K4];   // 98304 B, row r: [r*K4 + (k4 ^ (r&7))]
    __shared__ float4 xh[16 * K4];      // 49152 B, row b: [b*K4 + (k4 ^ (b&7))]
    __shared__ float  zsum[2][512];     //  4096 B, [parity][r*16 + b]

    const int wg = blockIdx.x;
    const int jb = wg & 63;
    const int bg = wg >> 6;
    const int b0 = bg * 16;
    const int j0 = jb * 8;
    const int tid = threadIdx.x;
    const int ks = tid >> 5;          // 0..15 K-slice
    const int ct = (tid >> 2) & 7;    // = jj
    const int bt = tid & 3;

    const float4* x4g = (const float4*)x;
    float* lds_f = (float*)xh;        // scalar view for swizzled h staging

    // ---- stage weights into LDS once (swizzled) ----
    for (int i = tid; i < 32 * K4; i += 512) {
        int r = i / K4;
        int k4 = i - r * K4;
        int col = (r >> 3) * HH + j0 + (r & 7);
        w_lds[r * K4 + (k4 ^ (r & 7))] =
            ((const float4*)(vut + (long)col * KX))[k4];
    }
    // ---- per-thread bias for zsum entry tid (r=tid>>4, b=tid&15) ----
    const int zr = tid >> 4;
    const float biasreg = bias[(zr >> 3) * HH + j0 + (zr & 7)];
    zsum[0][tid] = biasreg;

    float creg = 0.f;   // cell state for combiner threads (tid<128)

    // ---- x prefetch regs: items {tid, tid+512} of 1024 float4 ----
    const int xb1 = tid >> 6, xk1 = tid & 63;
    const int xb2 = 8 + xb1;
    float4 xp1 = x4g[((long)(b0 + xb1) * TT + 0) * 64 + xk1];
    float4 xp2 = x4g[((long)(b0 + xb2) * TT + 0) * 64 + xk1];

    // LDS base pointers for GEMM
    const float4* wl0 = &w_lds[(ct) * K4];
    const float4* wl1 = &w_lds[(8 + ct) * K4];
    const float4* wl2 = &w_lds[(16 + ct) * K4];
    const float4* wl3 = &w_lds[(24 + ct) * K4];
    const float4* xr0 = &xh[(bt) * K4];
    const float4* xr1 = &xh[(bt + 4) * K4];
    const float4* xr2 = &xh[(bt + 8) * K4];
    const float4* xr3 = &xh[(bt + 12) * K4];

    unsigned* const myflag = &flags[bg * 64 + jb];

    for (int t = 0; t < TT; ++t) {
        const int p = t & 1;
        const float* hp = h + p * (BB * HH);
        float* hn = h + (1 - p) * (BB * HH);

        // ---- (a) stage x-part from prefetch regs; issue next-x loads ----
        xh[xb1 * K4 + (xk1 ^ (xb1 & 7))] = xp1;
        xh[xb2 * K4 + (xk1 ^ (xb2 & 7))] = xp2;
        if (t + 1 < TT) {
            xp1 = x4g[((long)(b0 + xb1) * TT + (t + 1)) * 64 + xk1];
            xp2 = x4g[((long)(b0 + xb2) * TT + (t + 1)) * 64 + xk1];
        }

        // ---- (b) wait for this group's 64 producers (relaxed, no inv ops) ----
        if (t > 0 && tid < 64) {
            const unsigned want = (unsigned)t;
            while (__hip_atomic_load(&flags[bg * 64 + tid], __ATOMIC_RELAXED,
                                     __HIP_MEMORY_SCOPE_AGENT) < want) {
                __builtin_amdgcn_s_sleep(2);
            }
        }
        __syncthreads();

        // ---- (c) stage h: 8192 floats via coherence-point loads ----
        #pragma unroll
        for (int s = 0; s < 16; ++s) {
            int i = tid + s * 512;            // 0..8191
            int b = i >> 9, j = i & 511;      // batch-local, hidden idx
            float v = __hip_atomic_load(&hp[(b0 + b) * HH + j], __ATOMIC_RELAXED,
                                        __HIP_MEMORY_SCOPE_AGENT);
            int k4 = 64 + (j >> 2);
            lds_f[(b * K4 + (k4 ^ (b & 7))) * 4 + (j & 3)] = v;
        }
        __syncthreads();

        // ---- (d) GEMM: 4 gate-cols x 4 batches per thread, K-slice of 48 ----
        float4 acc[4][4];
        #pragma unroll
        for (int g = 0; g < 4; ++g)
            #pragma unroll
            for (int s = 0; s < 4; ++s)
                acc[g][s] = make_float4(0.f, 0.f, 0.f, 0.f);

        #pragma unroll
        for (int it = 0; it < 12; ++it) {
            const int k4 = ks * 12 + it;
            const int kw  = k4 ^ ct;
            const int kh0 = k4 ^ bt;
            const int kh1 = k4 ^ (bt + 4);
            float4 w0v = wl0[kw], w1v = wl1[kw], w2v = wl2[kw], w3v = wl3[kw];
            float4 h0v = xr0[kh0], h1v = xr1[kh1], h2v = xr2[kh0], h3v = xr3[kh1];
            FMA4(acc[0][0], w0v, h0v); FMA4(acc[0][1], w0v, h1v);
            FMA4(acc[0][2], w0v, h2v); FMA4(acc[0][3], w0v, h3v);
            FMA4(acc[1][0], w1v, h0v); FMA4(acc[1][1], w1v, h1v);
            FMA4(acc[1][2], w1v, h2v); FMA4(acc[1][3], w1v, h3v);
            FMA4(acc[2][0], w2v, h0v); FMA4(acc[2][1], w2v, h1v);
            FMA4(acc[2][2], w2v, h2v); FMA4(acc[2][3], w2v, h3v);
            FMA4(acc[3][0], w3v, h0v); FMA4(acc[3][1], w3v, h1v);
            FMA4(acc[3][2], w3v, h2v); FMA4(acc[3][3], w3v, h3v);
        }
        #pragma unroll
        for (int g = 0; g < 4; ++g) {
            #pragma unroll
            for (int s = 0; s < 4; ++s) {
                float4 a = acc[g][s];
                float z = (a.x + a.y) + (a.z + a.w);
                atomicAdd(&zsum[p][(g * 8 + ct) * 16 + (bt + 4 * s)], z);
            }
        }
        __syncthreads();

        // ---- (e) re-init other parity buffer + gate combine + h publish ----
        zsum[1 - p][tid] = biasreg;
        if (tid < 128) {
            const int b = tid >> 3, jj = tid & 7;
            float zi = zsum[p][(jj) * 16 + b];
            float zf = zsum[p][(8 + jj) * 16 + b];
            float zg = zsum[p][(16 + jj) * 16 + b];
            float zo = zsum[p][(24 + jj) * 16 + b];
            float iv = tanhf(zi);
            float fv = tanhf(zf);
            float gv = tanhf(zg);
            float ov = tanhf(zo);
            float c2 = fv * creg + iv * gv;
            float h2 = ov * tanhf(c2);
            creg = c2;
            // publish h at the coherence point (no fence needed)
            __hip_atomic_store(&hn[(b0 + b) * HH + (j0 + jj)], h2,
                               __ATOMIC_RELAXED, __HIP_MEMORY_SCOPE_AGENT);
            out[CTXF + ((long)((b0 + b) * TT + t)) * KX + DD + (j0 + jj)] = h2;
            if (t == TT - 1) out[(long)(b0 + b) * KX + DD + (j0 + jj)] = h2;
        }
        __syncthreads();   // drains vmcnt(0): h stores ACKED at coherence point
        if (tid == 0) {
            __hip_atomic_store(myflag, (unsigned)(t + 1),
                               __ATOMIC_RELAXED, __HIP_MEMORY_SCOPE_AGENT);
        }
    }
}

// ---------------------------------------------------------------------------
extern "C" void kernel_launch(void* const* d_in, const int* in_sizes, int n_in,
                              void* d_out, int out_size, void* d_ws, size_t ws_size,
                              hipStream_t stream) {
    (void)in_sizes; (void)n_in; (void)out_size; (void)ws_size;
    const float* x    = (const float*)d_in[0];
    const float* Wm   = (const float*)d_in[1];
    const float* Um   = (const float*)d_in[2];
    const float* bias = (const float*)d_in[3];
    float* out = (float*)d_out;
    float* ws  = (float*)d_ws;

    float* vut      = ws;                          // 2048*768 floats
    float* h        = ws + 1572864;                // 2 * 64*512 floats
    unsigned* flags = (unsigned*)(ws + 1572864 + 65536);  // 256 flags

    hipLaunchKernelGGL(pack_vut, dim3(64, 24), dim3(256), 0, stream, Wm, Um, vut);
    hipLaunchKernelGGL(init_state, dim3(256), dim3(256), 0, stream, h, flags);
    hipLaunchKernelGGL(xcopy, dim3(8209), dim3(256), 0, stream, x, out);

    void* args[] = {(void*)&vut, (void*)&bias, (void*)&x, (void*)&h,
                    (void*)&flags, (void*)&out};
    hipLaunchCooperativeKernel((const void*)lstm_persist, dim3(256), dim3(512),
                               args, 0, stream);
}

// Round 8
// 8035.921 us; speedup vs baseline: 3.4091x; 1.1306x over previous
//
#include <hip/hip_runtime.h>
#include <math.h>

// Problem constants
#define BB 64      // batch
#define TT 512     // time steps
#define DD 256     // input dim
#define HH 512     // hidden dim
#define GG 2048    // 4*H
#define KX 768     // D+H concat K
#define K4 192     // KX/4 float4s per row
#define CTXF 49152 // context_state floats; traj_h starts after

// ---------------------------------------------------------------------------
// pack VU^T: vut[col][k] = k<D ? W[k][col] : U[k-D][col]
// ---------------------------------------------------------------------------
__global__ void pack_vut(const float* __restrict__ Wm, const float* __restrict__ Um,
                         float* __restrict__ vut) {
    __shared__ float tile[32][33];
    int k0 = blockIdx.x * 32;   // col block (2048)
    int j0 = blockIdx.y * 32;   // K block (768)
    int lx = threadIdx.x & 31;
    int ly = threadIdx.x >> 5;
    for (int r = ly; r < 32; r += 8) {
        int j = j0 + r, k = k0 + lx;
        tile[r][lx] = (j < DD) ? Wm[j * GG + k] : Um[(j - DD) * GG + k];
    }
    __syncthreads();
    for (int r = ly; r < 32; r += 8) {
        int k = k0 + r, j = j0 + lx;
        vut[(long)k * KX + j] = tile[lx][r];
    }
}

// zero h double-buffer + sync flags (ws is re-poisoned 0xAA before every launch)
__global__ void init_state(float* __restrict__ h, unsigned* __restrict__ flags) {
    int idx = blockIdx.x * 256 + threadIdx.x;
    if (idx < 2 * BB * HH) h[idx] = 0.f;
    if (idx < 256) flags[idx] = 0u;
}

// ---------------------------------------------------------------------------
// copy x into traj_h[:, :, 0:256] and context_state[:, 0:256]
// ---------------------------------------------------------------------------
__global__ void xcopy(const float* __restrict__ x, float* __restrict__ out) {
    const long n_traj = (long)BB * TT * (DD / 4);
    long idx = (long)blockIdx.x * 256 + threadIdx.x;
    const float4* x4 = (const float4*)x;
    float4* out4 = (float4*)out;
    if (idx < n_traj) {
        long bt = idx / (DD / 4);
        int d4 = (int)(idx % (DD / 4));
        out4[(CTXF / 4) + bt * (KX / 4) + d4] = x4[idx];
    } else if (idx < n_traj + BB * (DD / 4)) {
        long f = idx - n_traj;
        int b = (int)(f / (DD / 4)), d4 = (int)(f % (DD / 4));
        out4[(long)b * (KX / 4) + d4] = x4[((long)b * TT + (TT - 1)) * (DD / 4) + d4];
    }
}

// ---------------------------------------------------------------------------
// Persistent LSTM. 256 WGs x 512 threads, cooperative (co-residency only).
// WG(jb=wg&63, bg=wg>>6): j in [jb*8,+8) x batches [bg*16,+16).
//
// Fence-free cross-WG sync (R6 protocol, R7 chain edits):
//   - all h/flag traffic = agent-scope RELAXED atomics at the coherence point
//     (MALL); no wbl2/inv cache ops anywhere.
//   - producer: combine -> h atomic-stores -> __syncthreads (vmcnt(0) drain:
//     stores ACKED at MALL) -> tid0 flag=t+1 -> THEN deferred out/traj writes
//     (HBM store tail off the critical path).
//   - consumer: GEMM x-part FIRST (needs no h), then poll flags, then stage h.
// Anti-overwrite: producer reaching step t+1's h-write passed the t+1 poll,
// which implies every group member finished step t and already read the
// buffer being overwritten.
// ---------------------------------------------------------------------------
#define FMA4(A, Wv, Hv) \
    A.x += Wv.x * Hv.x; A.y += Wv.y * Hv.y; A.z += Wv.z * Hv.z; A.w += Wv.w * Hv.w;

__global__ __launch_bounds__(512) void lstm_persist(
    const float* __restrict__ vut, const float* __restrict__ bias,
    const float* __restrict__ x, float* __restrict__ h,
    unsigned* __restrict__ flags, float* __restrict__ out)
{
    __shared__ float4 w_lds[32 * K4];   // 98304 B, row r: [r*K4 + (k4 ^ (r&7))]
    __shared__ float4 xh[16 * K4];      // 49152 B, row b: [b*K4 + (k4 ^ (b&7))]
    __shared__ float  zsum[2][512];     //  4096 B, [parity][r*16 + b]

    const int wg = blockIdx.x;
    const int jb = wg & 63;
    const int bg = wg >> 6;
    const int b0 = bg * 16;
    const int j0 = jb * 8;
    const int tid = threadIdx.x;
    const int ks = tid >> 5;          // 0..15 K-slice
    const int ct = (tid >> 2) & 7;    // = jj
    const int bt = tid & 3;

    const float4* x4g = (const float4*)x;

    // ---- stage weights into LDS once (swizzled) ----
    for (int i = tid; i < 32 * K4; i += 512) {
        int r = i / K4;
        int k4 = i - r * K4;
        int col = (r >> 3) * HH + j0 + (r & 7);
        w_lds[r * K4 + (k4 ^ (r & 7))] =
            ((const float4*)(vut + (long)col * KX))[k4];
    }
    // ---- per-thread bias for zsum entry tid (r=tid>>4, b=tid&15) ----
    const int zr = tid >> 4;
    const float biasreg = bias[(zr >> 3) * HH + j0 + (zr & 7)];
    zsum[0][tid] = biasreg;

    float creg = 0.f;   // cell state for combiner threads (tid<128)

    // ---- x prefetch regs: items {tid, tid+512} of 1024 float4 ----
    const int xb1 = tid >> 6, xk1 = tid & 63;
    const int xb2 = 8 + xb1;
    float4 xp1 = x4g[((long)(b0 + xb1) * TT + 0) * 64 + xk1];
    float4 xp2 = x4g[((long)(b0 + xb2) * TT + 0) * 64 + xk1];

    // LDS base pointers for GEMM
    const float4* wl0 = &w_lds[(ct) * K4];
    const float4* wl1 = &w_lds[(8 + ct) * K4];
    const float4* wl2 = &w_lds[(16 + ct) * K4];
    const float4* wl3 = &w_lds[(24 + ct) * K4];
    const float4* xr0 = &xh[(bt) * K4];
    const float4* xr1 = &xh[(bt + 4) * K4];
    const float4* xr2 = &xh[(bt + 8) * K4];
    const float4* xr3 = &xh[(bt + 12) * K4];

    unsigned* const myflag = &flags[bg * 64 + jb];

    for (int t = 0; t < TT; ++t) {
        const int p = t & 1;
        const float* hp = h + p * (BB * HH);
        float* hn = h + (1 - p) * (BB * HH);

        // ---- (a) stage x-part into LDS from prefetch regs; issue next-x ----
        xh[xb1 * K4 + (xk1 ^ (xb1 & 7))] = xp1;
        xh[xb2 * K4 + (xk1 ^ (xb2 & 7))] = xp2;
        if (t + 1 < TT) {
            xp1 = x4g[((long)(b0 + xb1) * TT + (t + 1)) * 64 + xk1];
            xp2 = x4g[((long)(b0 + xb2) * TT + (t + 1)) * 64 + xk1];
        }
        __syncthreads();   // x-region of xh ready (h-region not touched yet)

        // ---- (b) GEMM x-part: k4 in [0,64), needs no h ----
        float4 acc[4][4];
        #pragma unroll
        for (int g = 0; g < 4; ++g)
            #pragma unroll
            for (int s = 0; s < 4; ++s)
                acc[g][s] = make_float4(0.f, 0.f, 0.f, 0.f);

        #pragma unroll
        for (int it = 0; it < 4; ++it) {
            const int k4 = ks * 4 + it;        // 0..63
            const int kw  = k4 ^ ct;
            const int kh0 = k4 ^ bt;
            const int kh1 = k4 ^ (bt + 4);
            float4 w0v = wl0[kw], w1v = wl1[kw], w2v = wl2[kw], w3v = wl3[kw];
            float4 h0v = xr0[kh0], h1v = xr1[kh1], h2v = xr2[kh0], h3v = xr3[kh1];
            FMA4(acc[0][0], w0v, h0v); FMA4(acc[0][1], w0v, h1v);
            FMA4(acc[0][2], w0v, h2v); FMA4(acc[0][3], w0v, h3v);
            FMA4(acc[1][0], w1v, h0v); FMA4(acc[1][1], w1v, h1v);
            FMA4(acc[1][2], w1v, h2v); FMA4(acc[1][3], w1v, h3v);
            FMA4(acc[2][0], w2v, h0v); FMA4(acc[2][1], w2v, h1v);
            FMA4(acc[2][2], w2v, h2v); FMA4(acc[2][3], w2v, h3v);
            FMA4(acc[3][0], w3v, h0v); FMA4(acc[3][1], w3v, h1v);
            FMA4(acc[3][2], w3v, h2v); FMA4(acc[3][3], w3v, h3v);
        }

        // ---- (c) wait for this group's 64 producers (relaxed, no inv ops) ----
        if (t > 0 && tid < 64) {
            const unsigned want = (unsigned)t;
            while (__hip_atomic_load(&flags[bg * 64 + tid], __ATOMIC_RELAXED,
                                     __HIP_MEMORY_SCOPE_AGENT) < want) {
                __builtin_amdgcn_s_sleep(1);
            }
        }
        __syncthreads();

        // ---- (d) stage h: 64-bit coherence-point loads -> swizzled LDS ----
        const unsigned long long* hp64 = (const unsigned long long*)hp;
        #pragma unroll
        for (int s = 0; s < 4; ++s) {
            int i = tid + s * 512;            // float4 index 0..2047
            int b = i >> 7, k4h = i & 127;
            long base2 = (long)(b0 + b) * 256 + (long)k4h * 2;
            unsigned long long lo = __hip_atomic_load(&hp64[base2], __ATOMIC_RELAXED,
                                                      __HIP_MEMORY_SCOPE_AGENT);
            unsigned long long hi = __hip_atomic_load(&hp64[base2 + 1], __ATOMIC_RELAXED,
                                                      __HIP_MEMORY_SCOPE_AGENT);
            float4 v;
            v.x = __uint_as_float((unsigned)lo);
            v.y = __uint_as_float((unsigned)(lo >> 32));
            v.z = __uint_as_float((unsigned)hi);
            v.w = __uint_as_float((unsigned)(hi >> 32));
            int k4 = 64 + k4h;
            xh[b * K4 + (k4 ^ (b & 7))] = v;
        }
        __syncthreads();

        // ---- (e) GEMM h-part: k4 in [64,192); then zsum reduce ----
        #pragma unroll
        for (int it = 0; it < 8; ++it) {
            const int k4 = 64 + ks * 8 + it;   // 64..191
            const int kw  = k4 ^ ct;
            const int kh0 = k4 ^ bt;
            const int kh1 = k4 ^ (bt + 4);
            float4 w0v = wl0[kw], w1v = wl1[kw], w2v = wl2[kw], w3v = wl3[kw];
            float4 h0v = xr0[kh0], h1v = xr1[kh1], h2v = xr2[kh0], h3v = xr3[kh1];
            FMA4(acc[0][0], w0v, h0v); FMA4(acc[0][1], w0v, h1v);
            FMA4(acc[0][2], w0v, h2v); FMA4(acc[0][3], w0v, h3v);
            FMA4(acc[1][0], w1v, h0v); FMA4(acc[1][1], w1v, h1v);
            FMA4(acc[1][2], w1v, h2v); FMA4(acc[1][3], w1v, h3v);
            FMA4(acc[2][0], w2v, h0v); FMA4(acc[2][1], w2v, h1v);
            FMA4(acc[2][2], w2v, h2v); FMA4(acc[2][3], w2v, h3v);
            FMA4(acc[3][0], w3v, h0v); FMA4(acc[3][1], w3v, h1v);
            FMA4(acc[3][2], w3v, h2v); FMA4(acc[3][3], w3v, h3v);
        }
        #pragma unroll
        for (int g = 0; g < 4; ++g) {
            #pragma unroll
            for (int s = 0; s < 4; ++s) {
                float4 a = acc[g][s];
                float z = (a.x + a.y) + (a.z + a.w);
                atomicAdd(&zsum[p][(g * 8 + ct) * 16 + (bt + 4 * s)], z);
            }
        }
        __syncthreads();

        // ---- (f) re-init other parity; combine; publish h; flag ----
        zsum[1 - p][tid] = biasreg;
        float h2 = 0.f;
        int gb = 0, gj = 0;
        if (tid < 128) {
            const int b = tid >> 3, jj = tid & 7;
            float zi = zsum[p][(jj) * 16 + b];
            float zf = zsum[p][(8 + jj) * 16 + b];
            float zg = zsum[p][(16 + jj) * 16 + b];
            float zo = zsum[p][(24 + jj) * 16 + b];
            float iv = tanhf(zi);
            float fv = tanhf(zf);
            float gv = tanhf(zg);
            float ov = tanhf(zo);
            float c2 = fv * creg + iv * gv;
            h2 = ov * tanhf(c2);
            creg = c2;
            gb = b0 + b; gj = j0 + jj;
            __hip_atomic_store(&hn[gb * HH + gj], h2,
                               __ATOMIC_RELAXED, __HIP_MEMORY_SCOPE_AGENT);
        }
        __syncthreads();   // vmcnt(0) drain: all h stores ACKED at MALL
        if (tid == 0) {
            __hip_atomic_store(myflag, (unsigned)(t + 1),
                               __ATOMIC_RELAXED, __HIP_MEMORY_SCOPE_AGENT);
        }

        // ---- (g) deferred out/traj writes (off the inter-WG critical path) ----
        if (tid < 128) {
            out[CTXF + ((long)(gb * TT + t)) * KX + DD + gj] = h2;
            if (t == TT - 1) out[(long)gb * KX + DD + gj] = h2;
        }
    }
}

// ---------------------------------------------------------------------------
extern "C" void kernel_launch(void* const* d_in, const int* in_sizes, int n_in,
                              void* d_out, int out_size, void* d_ws, size_t ws_size,
                              hipStream_t stream) {
    (void)in_sizes; (void)n_in; (void)out_size; (void)ws_size;
    const float* x    = (const float*)d_in[0];
    const float* Wm   = (const float*)d_in[1];
    const float* Um   = (const float*)d_in[2];
    const float* bias = (const float*)d_in[3];
    float* out = (float*)d_out;
    float* ws  = (float*)d_ws;

    float* vut      = ws;                          // 2048*768 floats
    float* h        = ws + 1572864;                // 2 * 64*512 floats
    unsigned* flags = (unsigned*)(ws + 1572864 + 65536);  // 256 flags

    hipLaunchKernelGGL(pack_vut, dim3(64, 24), dim3(256), 0, stream, Wm, Um, vut);
    hipLaunchKernelGGL(init_state, dim3(256), dim3(256), 0, stream, h, flags);
    hipLaunchKernelGGL(xcopy, dim3(8209), dim3(256), 0, stream, x, out);

    void* args[] = {(void*)&vut, (void*)&bias, (void*)&x, (void*)&h,
                    (void*)&flags, (void*)&out};
    hipLaunchCooperativeKernel((const void*)lstm_persist, dim3(256), dim3(512),
                               args, 0, stream);
}